// Round 3
// baseline (972.235 us; speedup 1.0000x reference)
//
#include <hip/hip_runtime.h>
#include <math.h>

#define Bn   4
#define CINn 16
#define HIDn 16
#define Tn   31
#define Hn   128
#define Wn   128

#define NS    14                  // K-steps: 28 taps (27 real + 1 zero-pad) x 16 cin, K=32 each
#define WSTR  48                  // LDS bytes per w-position (16 f16 used + 8 pad) -> 16B aligned
#define ROWB  (130*WSTR)          // 6240 B per staged row (w = -1..128)
#define SLOTB (3*ROWB)            // 18720 B per time slice (rows h-1..h+1)
#define NSLOT 4                   // 4-slot ring: single barrier per t is provably safe
#define LDSB  (NSLOT*SLOTB)       // 74880 B

typedef _Float16 half8 __attribute__((ext_vector_type(8)));
typedef float    f32x4 __attribute__((ext_vector_type(4)));

// tap = kd*9 + kh*3 + kw ; entry 27 is an address clamp (its weight is 0)
constexpr int KDt[28] = {0,0,0,0,0,0,0,0,0, 1,1,1,1,1,1,1,1,1, 2,2,2,2,2,2,2,2,2, 2};
constexpr int KHt[28] = {0,0,0,1,1,1,2,2,2, 0,0,0,1,1,1,2,2,2, 0,0,0,1,1,1,2,2,2, 2};
constexpr int KWt[28] = {0,1,2,0,1,2,0,1,2, 0,1,2,0,1,2,0,1,2, 0,1,2,0,1,2,0,1,2, 2};

__device__ __forceinline__ float sigmoidf_(float x) { return 1.f / (1.f + __expf(-x)); }
__device__ __forceinline__ float tanhf_(float x)    { return 2.f / (1.f + __expf(-2.f * x)) - 1.f; }

// Repack W[oc][cin][kd][kh][kw] into per-lane A-fragment layout, f16:
// WA[s][m][lane][j] : g = lane>>4 ; tap = 2s + (g>>1) ; cin = (g&1)*8 + j ; oc = m*16 + (lane&15)
__global__ void repack_wa_kernel(const float* __restrict__ W, _Float16* __restrict__ WA) {
    int idx = blockIdx.x * blockDim.x + threadIdx.x;
    if (idx >= NS * 4 * 64 * 8) return;
    int j    = idx & 7;
    int lane = (idx >> 3) & 63;
    int m    = (idx >> 9) & 3;
    int s    = idx >> 11;
    int g    = lane >> 4;
    int tap  = 2 * s + (g >> 1);
    int cin  = (g & 1) * 8 + j;
    int oc   = m * 16 + (lane & 15);
    float v  = (tap < 27) ? W[(size_t)(oc * CINn + cin) * 27 + tap] : 0.f;
    WA[idx] = (_Float16)v;
}

// One workgroup per (b, h): 512 threads = 8 waves, each wave owns 16 w-cols
// (1 MFMA N-tile). Implicit-GEMM conv via mfma_f32_16x16x32_f16, recurrence
// fused (c in registers). 4-slot LDS ring + async stage split:
//   iter t: commit slice t+1 (regs->LDS), issue loads for t+2 (->regs, no
//   wait), barrier, compute t from slots t-1,t,t+1. One barrier per t.
// amdgpu_waves_per_eu(4,4): LDS caps us at 2 blocks/CU (= 4 waves/EU); pin the
// compiler to that target so it uses the full 128-VGPR budget instead of
// squeezing to 64 and spilling to scratch (round-2 pathology: 2.9 GB of
// spill traffic through HBM because dynamic LDS hid the real occupancy cap).
__global__ __launch_bounds__(512) __attribute__((amdgpu_waves_per_eu(4, 4)))
void qrnn_mfma_kernel(const float* __restrict__ X, const _Float16* __restrict__ WA,
                      const float* __restrict__ bias, float* __restrict__ out) {
    extern __shared__ char smem[];

    const int tid  = threadIdx.x;
    const int lane = tid & 63;
    const int wv   = tid >> 6;            // wave 0..7 -> w segment [wv*16, wv*16+16)

    // XCD-bijective swizzle (512 wgs, 8 XCDs): contiguous h per XCD L2
    const int swz = (blockIdx.x & 7) * 64 + (blockIdx.x >> 3);
    const int b = swz >> 7;
    const int h = swz & 127;

    const size_t strideT = (size_t)Hn * Wn;        // 16384
    const size_t strideC = (size_t)Tn * strideT;   // 507904
    const float* Xb = X + (size_t)b * CINn * strideC;

    const int lane15  = lane & 15;
    const int g       = lane >> 4;        // k-group 0..3
    const int ghi     = g >> 1;           // which tap of the K-step pair
    const int laneoff = lane15 * WSTR + (g & 1) * 16;
    const int wseg    = wv * 16;

    // bias per thread: hid = g*4 + r (C-frag row = (lane>>4)*4 + reg)
    float bz[4], bfv[4], bov[4], biv[4];
    #pragma unroll
    for (int r = 0; r < 4; r++) {
        int hid = g * 4 + r;
        bz[r]  = bias[hid];
        bfv[r] = bias[HIDn + hid];
        bov[r] = bias[2 * HIDn + hid];
        biv[r] = bias[3 * HIDn + hid];
    }

    // --- staging: one (row,wpos) position per thread (390 positions) ---
    const bool sown = (tid < 3 * 130);
    const int  srow = (tid >= 260) ? 2 : (tid >= 130) ? 1 : 0;
    const int  swp  = tid - srow * 130;   // 0..129 -> w = swp-1
    const int  hr   = h - 1 + srow;
    const int  wa   = swp - 1;
    const bool sok  = sown && (hr >= 0) && (hr < Hn) && (wa >= 0) && (wa < Wn);
    const float* psrc = Xb + (ptrdiff_t)hr * Wn + wa;   // + u*strideT at issue
    const int  pdst = srow * ROWB + swp * WSTR;

    float pf[16];   // in-flight slice data (raw f32; cvt deferred to commit)

    auto stage_issue = [&](int u) {
        #pragma unroll
        for (int c8 = 0; c8 < 16; c8++) pf[c8] = 0.f;
        if (sok && u >= 0 && u < Tn) {
            const float* s = psrc + (ptrdiff_t)u * (ptrdiff_t)strideT;
            #pragma unroll
            for (int c8 = 0; c8 < 16; c8++) pf[c8] = s[(size_t)c8 * strideC];
        }
    };
    auto stage_commit = [&](int u) {
        if (sown) {
            half8 h0, h1;
            #pragma unroll
            for (int c8 = 0; c8 < 8; c8++) { h0[c8] = (_Float16)pf[c8]; h1[c8] = (_Float16)pf[8 + c8]; }
            char* dst = smem + (((u % NSLOT) + NSLOT) % NSLOT) * SLOTB + pdst;
            *reinterpret_cast<half8*>(dst)      = h0;
            *reinterpret_cast<half8*>(dst + 16) = h1;
        }
    };

    // prologue: slot 3 (u=-1) = zeros; commit u=0; issue u=1
    if (sown) {
        half8 zz = {};
        char* dst = smem + 3 * SLOTB + pdst;
        *reinterpret_cast<half8*>(dst)      = zz;
        *reinterpret_cast<half8*>(dst + 16) = zz;
    }
    stage_issue(0);
    stage_commit(0);
    stage_issue(1);

    float cst[4] = {0.f, 0.f, 0.f, 0.f};
    float* outT = out + (size_t)b * HIDn * strideC + (size_t)h * Wn + wseg + lane15;

    for (int t = 0; t < Tn; t++) {
        stage_commit(t + 1);                // regs -> slot (t+1)%4
        stage_issue(t + 2);                 // global loads in flight across compute
        __syncthreads();

        // ring slot byte-bases for kd = 0,1,2  (slices t-1, t, t+1)
        const int sb[3] = { ((t + 3) % NSLOT) * SLOTB, (t % NSLOT) * SLOTB, ((t + 1) % NSLOT) * SLOTB };

        f32x4 acc[4];
        #pragma unroll
        for (int m = 0; m < 4; m++) acc[m] = (f32x4)(0.f);

        #pragma unroll
        for (int s = 0; s < NS; s++) {
            const half8 a0 = *reinterpret_cast<const half8*>(WA + ((size_t)(s * 4 + 0) * 64 + lane) * 8);
            const half8 a1 = *reinterpret_cast<const half8*>(WA + ((size_t)(s * 4 + 1) * 64 + lane) * 8);
            const half8 a2 = *reinterpret_cast<const half8*>(WA + ((size_t)(s * 4 + 2) * 64 + lane) * 8);
            const half8 a3 = *reinterpret_cast<const half8*>(WA + ((size_t)(s * 4 + 3) * 64 + lane) * 8);

            const int tA = 2 * s, tB = 2 * s + 1;        // compile-time
            const int offA = sb[KDt[tA]] + KHt[tA] * ROWB + KWt[tA] * WSTR;
            const int offB = sb[KDt[tB]] + KHt[tB] * ROWB + KWt[tB] * WSTR;
            const int off  = (ghi ? offB : offA) + laneoff;

            const half8 bf = *reinterpret_cast<const half8*>(smem + off + wseg * WSTR);
            acc[0] = __builtin_amdgcn_mfma_f32_16x16x32_f16(a0, bf, acc[0], 0, 0, 0);
            acc[1] = __builtin_amdgcn_mfma_f32_16x16x32_f16(a1, bf, acc[1], 0, 0, 0);
            acc[2] = __builtin_amdgcn_mfma_f32_16x16x32_f16(a2, bf, acc[2], 0, 0, 0);
            acc[3] = __builtin_amdgcn_mfma_f32_16x16x32_f16(a3, bf, acc[3], 0, 0, 0);
        }

        // epilogue: oc-tile m = gate m (z,f,o,i) for hid = g*4+r, col = wseg+lane15
        #pragma unroll
        for (int r = 0; r < 4; r++) {
            float z = tanhf_   (acc[0][r] + bz[r]);
            float f = sigmoidf_(acc[1][r] + bfv[r]);
            float o = sigmoidf_(acc[2][r] + bov[r]);
            float i = sigmoidf_(acc[3][r] + biv[r]);
            float c = f * cst[r] + i * z;
            cst[r] = c;
            outT[(size_t)(g * 4 + r) * strideC + (size_t)t * strideT] = o * c;
        }
        // no trailing barrier: 4-slot ring makes next iter's writes disjoint
        // from any slot a <=1-iteration-lagging wave can still be reading.
    }
}

extern "C" void kernel_launch(void* const* d_in, const int* in_sizes, int n_in,
                              void* d_out, int out_size, void* d_ws, size_t ws_size,
                              hipStream_t stream) {
    const float* X    = (const float*)d_in[0];
    const float* W    = (const float*)d_in[1];
    const float* bias = (const float*)d_in[2];
    float* out = (float*)d_out;
    _Float16* WA = (_Float16*)d_ws;   // 14*4*64*8 f16 = 57344 B

    repack_wa_kernel<<<(NS * 4 * 64 * 8 + 255) / 256, 256, 0, stream>>>(W, WA);
    qrnn_mfma_kernel<<<Bn * Hn, 512, LDSB, stream>>>(X, WA, bias, out);
}

// Round 5
// 970.782 us; speedup vs baseline: 1.0015x; 1.0015x over previous
//
#include <hip/hip_runtime.h>
#include <math.h>

#define Bn   4
#define CINn 16
#define HIDn 16
#define Tn   31
#define Hn   128
#define Wn   128

#define NS    14                  // K-steps: 28 taps (27 real + 1 zero-pad) x 16 cin, K=32 each
#define WSTR  48                  // LDS bytes per w-position (16 f16 used + 8 pad) -> 16B aligned
#define ROWB  (130*WSTR)          // 6240 B per staged row (w = -1..128)
#define SLOTB (3*ROWB)            // 18720 B per time slice (rows h-1..h+1)
#define NSLOT 4                   // 4-slot ring: single barrier per t is provably safe
#define LDSB  (NSLOT*SLOTB)       // 74880 B

typedef _Float16 half8 __attribute__((ext_vector_type(8)));
typedef float    f32x4 __attribute__((ext_vector_type(4)));

// tap = kd*9 + kh*3 + kw ; entry 27 is an address clamp (its weight is 0)
constexpr int KDt[28] = {0,0,0,0,0,0,0,0,0, 1,1,1,1,1,1,1,1,1, 2,2,2,2,2,2,2,2,2, 2};
constexpr int KHt[28] = {0,0,0,1,1,1,2,2,2, 0,0,0,1,1,1,2,2,2, 0,0,0,1,1,1,2,2,2, 2};
constexpr int KWt[28] = {0,1,2,0,1,2,0,1,2, 0,1,2,0,1,2,0,1,2, 0,1,2,0,1,2,0,1,2, 2};

__device__ __forceinline__ float sigmoidf_(float x) { return 1.f / (1.f + __expf(-x)); }
__device__ __forceinline__ float tanhf_(float x)    { return 2.f / (1.f + __expf(-2.f * x)) - 1.f; }

// Repack W[oc][cin][kd][kh][kw] into per-lane A-fragment layout, f16:
// WA[s][m][lane][j] : g = lane>>4 ; tap = 2s + (g>>1) ; cin = (g&1)*8 + j ; oc = m*16 + (lane&15)
__global__ void repack_wa_kernel(const float* __restrict__ W, _Float16* __restrict__ WA) {
    int idx = blockIdx.x * blockDim.x + threadIdx.x;
    if (idx >= NS * 4 * 64 * 8) return;
    int j    = idx & 7;
    int lane = (idx >> 3) & 63;
    int m    = (idx >> 9) & 3;
    int s    = idx >> 11;
    int g    = lane >> 4;
    int tap  = 2 * s + (g >> 1);
    int cin  = (g & 1) * 8 + j;
    int oc   = m * 16 + (lane & 15);
    float v  = (tap < 27) ? W[(size_t)(oc * CINn + cin) * 27 + tap] : 0.f;
    WA[idx] = (_Float16)v;
}

// One workgroup per (b, h): 512 threads = 8 waves, each wave owns 16 w-cols
// (1 MFMA N-tile). Implicit-GEMM conv via mfma_f32_16x16x32_f16, recurrence
// fused (c in registers). 4-slot LDS ring + async stage split:
//   iter t: commit slice t+1 (regs->LDS), issue loads for t+2 (->regs, no
//   wait), barrier, compute t from slots t-1,t,t+1. One barrier per t.
// STATIC LDS is load-bearing: with extern __shared__ the compiler assumed
// LDS=0 -> targeted 8 waves/EU -> 64 VGPRs -> spilled pf[]/acc to scratch
// (rounds 2/3: 2.3 GB of spill traffic through HBM, VGPR_Count=64). Static
// 74880 B makes it derive the true 2-block/CU cap and use the 128-VGPR budget.
__global__ __launch_bounds__(512, 4)
void qrnn_mfma_kernel(const float* __restrict__ X, const _Float16* __restrict__ WA,
                      const float* __restrict__ bias, float* __restrict__ out) {
    __shared__ __align__(16) char smem[LDSB];

    const int tid  = threadIdx.x;
    const int lane = tid & 63;
    const int wv   = tid >> 6;            // wave 0..7 -> w segment [wv*16, wv*16+16)

    // XCD-bijective swizzle (512 wgs, 8 XCDs): contiguous h per XCD L2
    const int swz = (blockIdx.x & 7) * 64 + (blockIdx.x >> 3);
    const int b = swz >> 7;
    const int h = swz & 127;

    const size_t strideT = (size_t)Hn * Wn;        // 16384
    const size_t strideC = (size_t)Tn * strideT;   // 507904
    const float* Xb = X + (size_t)b * CINn * strideC;

    const int lane15  = lane & 15;
    const int g       = lane >> 4;        // k-group 0..3
    const int ghi     = g >> 1;           // which tap of the K-step pair
    const int laneoff = lane15 * WSTR + (g & 1) * 16;
    const int wseg    = wv * 16;

    // bias per thread: hid = g*4 + r (C-frag row = (lane>>4)*4 + reg)
    float bz[4], bfv[4], bov[4], biv[4];
    #pragma unroll
    for (int r = 0; r < 4; r++) {
        int hid = g * 4 + r;
        bz[r]  = bias[hid];
        bfv[r] = bias[HIDn + hid];
        bov[r] = bias[2 * HIDn + hid];
        biv[r] = bias[3 * HIDn + hid];
    }

    // --- staging: one (row,wpos) position per thread (390 positions) ---
    const bool sown = (tid < 3 * 130);
    const int  srow = (tid >= 260) ? 2 : (tid >= 130) ? 1 : 0;
    const int  swp  = tid - srow * 130;   // 0..129 -> w = swp-1
    const int  hr   = h - 1 + srow;
    const int  wa   = swp - 1;
    const bool sok  = sown && (hr >= 0) && (hr < Hn) && (wa >= 0) && (wa < Wn);
    const float* psrc = Xb + (ptrdiff_t)hr * Wn + wa;   // + u*strideT at issue
    const int  pdst = srow * ROWB + swp * WSTR;

    float pf[16];   // in-flight slice data (raw f32; cvt deferred to commit)

    auto stage_issue = [&](int u) {
        #pragma unroll
        for (int c8 = 0; c8 < 16; c8++) pf[c8] = 0.f;
        if (sok && u >= 0 && u < Tn) {
            const float* s = psrc + (ptrdiff_t)u * (ptrdiff_t)strideT;
            #pragma unroll
            for (int c8 = 0; c8 < 16; c8++) pf[c8] = s[(size_t)c8 * strideC];
        }
    };
    auto stage_commit = [&](int u) {
        if (sown) {
            half8 h0, h1;
            #pragma unroll
            for (int c8 = 0; c8 < 8; c8++) { h0[c8] = (_Float16)pf[c8]; h1[c8] = (_Float16)pf[8 + c8]; }
            char* dst = smem + (((u % NSLOT) + NSLOT) % NSLOT) * SLOTB + pdst;
            *reinterpret_cast<half8*>(dst)      = h0;
            *reinterpret_cast<half8*>(dst + 16) = h1;
        }
    };

    // prologue: slot 3 (u=-1) = zeros; commit u=0; issue u=1
    if (sown) {
        half8 zz = {};
        char* dst = smem + 3 * SLOTB + pdst;
        *reinterpret_cast<half8*>(dst)      = zz;
        *reinterpret_cast<half8*>(dst + 16) = zz;
    }
    stage_issue(0);
    stage_commit(0);
    stage_issue(1);

    float cst[4] = {0.f, 0.f, 0.f, 0.f};
    float* outT = out + (size_t)b * HIDn * strideC + (size_t)h * Wn + wseg + lane15;

    for (int t = 0; t < Tn; t++) {
        stage_commit(t + 1);                // regs -> slot (t+1)%4
        stage_issue(t + 2);                 // global loads in flight across compute
        __syncthreads();

        // ring slot byte-bases for kd = 0,1,2  (slices t-1, t, t+1)
        const int sb[3] = { ((t + 3) % NSLOT) * SLOTB, (t % NSLOT) * SLOTB, ((t + 1) % NSLOT) * SLOTB };

        f32x4 acc[4];
        #pragma unroll
        for (int m = 0; m < 4; m++) acc[m] = (f32x4)(0.f);

        #pragma unroll
        for (int s = 0; s < NS; s++) {
            const half8 a0 = *reinterpret_cast<const half8*>(WA + ((size_t)(s * 4 + 0) * 64 + lane) * 8);
            const half8 a1 = *reinterpret_cast<const half8*>(WA + ((size_t)(s * 4 + 1) * 64 + lane) * 8);
            const half8 a2 = *reinterpret_cast<const half8*>(WA + ((size_t)(s * 4 + 2) * 64 + lane) * 8);
            const half8 a3 = *reinterpret_cast<const half8*>(WA + ((size_t)(s * 4 + 3) * 64 + lane) * 8);

            const int tA = 2 * s, tB = 2 * s + 1;        // compile-time
            const int offA = sb[KDt[tA]] + KHt[tA] * ROWB + KWt[tA] * WSTR;
            const int offB = sb[KDt[tB]] + KHt[tB] * ROWB + KWt[tB] * WSTR;
            const int off  = (ghi ? offB : offA) + laneoff;

            const half8 bf = *reinterpret_cast<const half8*>(smem + off + wseg * WSTR);
            acc[0] = __builtin_amdgcn_mfma_f32_16x16x32_f16(a0, bf, acc[0], 0, 0, 0);
            acc[1] = __builtin_amdgcn_mfma_f32_16x16x32_f16(a1, bf, acc[1], 0, 0, 0);
            acc[2] = __builtin_amdgcn_mfma_f32_16x16x32_f16(a2, bf, acc[2], 0, 0, 0);
            acc[3] = __builtin_amdgcn_mfma_f32_16x16x32_f16(a3, bf, acc[3], 0, 0, 0);
        }

        // epilogue: oc-tile m = gate m (z,f,o,i) for hid = g*4+r, col = wseg+lane15
        #pragma unroll
        for (int r = 0; r < 4; r++) {
            float z = tanhf_   (acc[0][r] + bz[r]);
            float f = sigmoidf_(acc[1][r] + bfv[r]);
            float o = sigmoidf_(acc[2][r] + bov[r]);
            float i = sigmoidf_(acc[3][r] + biv[r]);
            float c = f * cst[r] + i * z;
            cst[r] = c;
            outT[(size_t)(g * 4 + r) * strideC + (size_t)t * strideT] = o * c;
        }
        // no trailing barrier: 4-slot ring makes next iter's writes disjoint
        // from any slot a <=1-iteration-lagging wave can still be reading.
    }
}

extern "C" void kernel_launch(void* const* d_in, const int* in_sizes, int n_in,
                              void* d_out, int out_size, void* d_ws, size_t ws_size,
                              hipStream_t stream) {
    const float* X    = (const float*)d_in[0];
    const float* W    = (const float*)d_in[1];
    const float* bias = (const float*)d_in[2];
    float* out = (float*)d_out;
    _Float16* WA = (_Float16*)d_ws;   // 14*4*64*8 f16 = 57344 B

    repack_wa_kernel<<<(NS * 4 * 64 * 8 + 255) / 256, 256, 0, stream>>>(W, WA);
    qrnn_mfma_kernel<<<Bn * Hn, 512, 0, stream>>>(X, WA, bias, out);
}

// Round 8
// 484.597 us; speedup vs baseline: 2.0063x; 2.0033x over previous
//
#include <hip/hip_runtime.h>
#include <math.h>

#define Bn   4
#define CINn 16
#define HIDn 16
#define Tn   31
#define Hn   128
#define Wn   128

#define NS   14                   // K-steps: 28 taps (27 real + 1 zero-pad) x 16 cin, K=32 each

typedef _Float16 half8 __attribute__((ext_vector_type(8)));
typedef float    f32x4 __attribute__((ext_vector_type(4)));

// tap = kd*9 + kh*3 + kw ; entry 27 is an address clamp (its weight is 0)
constexpr int KDt[28] = {0,0,0,0,0,0,0,0,0, 1,1,1,1,1,1,1,1,1, 2,2,2,2,2,2,2,2,2, 2};
constexpr int KHt[28] = {0,0,0,1,1,1,2,2,2, 0,0,0,1,1,1,2,2,2, 0,0,0,1,1,1,2,2,2, 2};
constexpr int KWt[28] = {0,1,2,0,1,2,0,1,2, 0,1,2,0,1,2,0,1,2, 0,1,2,0,1,2,0,1,2, 2};

__device__ __forceinline__ float sigmoidf_(float x) { return 1.f / (1.f + __expf(-x)); }
__device__ __forceinline__ float tanhf_(float x)    { return 2.f / (1.f + __expf(-2.f * x)) - 1.f; }

// Repack W[oc][cin][kd][kh][kw] into per-lane A-fragment layout, f16 (both paths):
// WA[s][m][lane][j] : g = lane>>4 ; tap = 2s + (g>>1) ; cin = (g&1)*8 + j ; oc = m*16 + (lane&15)
__global__ void repack_wa_kernel(const float* __restrict__ W, _Float16* __restrict__ WA) {
    int idx = blockIdx.x * blockDim.x + threadIdx.x;
    if (idx >= NS * 4 * 64 * 8) return;
    int j    = idx & 7;
    int lane = (idx >> 3) & 63;
    int m    = (idx >> 9) & 3;
    int s    = idx >> 11;
    int g    = lane >> 4;
    int tap  = 2 * s + (g >> 1);
    int cin  = (g & 1) * 8 + j;
    int oc   = m * 16 + (lane & 15);
    float v  = (tap < 27) ? W[(size_t)(oc * CINn + cin) * 27 + tap] : 0.f;
    WA[idx] = (_Float16)v;
}

// =====================  FAST PATH  =====================
#define POSB    32                  // bytes per (row,wpos): 16 cin f16, contiguous
#define ROWF    (130*POSB)          // 4160 B per staged row (w = -1..128)
#define SLOTF   (3*ROWF)            // 12480 B per time slice (rows h-1..h+1)
#define LDSF    (4*SLOTF)           // 49920 B: 4-slot ring -> single barrier per t
// WA = 14*4*64*8 f16 = 28672 ELEMENTS = 57344 BYTES. Round 7 set XH_OFF=32768
// and the transpose overwrote WA's s=8..13 fragments (taps 16-27) -> absmax 7.3.
#define XH_OFF  65536
#define SLICE_B (Hn*Wn*CINn*2)      // 524288 B per (b,t) slice
#define WS_NEED ((size_t)XH_OFF + (size_t)Bn*Tn*SLICE_B)

// X[b][cin][t][h][w] f32 -> Xh[b][t][h][w][cin] f16 (cin contiguous, 16B-load-able)
__global__ __launch_bounds__(256)
void transpose_x_kernel(const float* __restrict__ X, _Float16* __restrict__ Xh) {
    int i   = blockIdx.x * 256 + threadIdx.x;      // over Bn*Tn*Hn*Wn = 2,031,616 (exact grid)
    int pos = i & 16383;
    int bu  = i >> 14;                             // b*31 + u
    int b   = bu / 31;
    int u   = bu - b * 31;
    const float* src = X + ((size_t)(b * CINn) * Tn + u) * 16384 + pos;
    half8 h0, h1;
    #pragma unroll
    for (int c = 0; c < 8; c++) h0[c] = (_Float16)src[(size_t)c * (Tn * 16384)];
    #pragma unroll
    for (int c = 0; c < 8; c++) h1[c] = (_Float16)src[(size_t)(c + 8) * (Tn * 16384)];
    half8* dst = (half8*)(Xh + (size_t)i * 16);
    dst[0] = h0; dst[1] = h1;
}

// One workgroup per (b,h): 256 threads = 4 waves, wave = 2 n-tiles x 4 oc-tiles
// (round-1 proven shape: this config gave VGPR=128, no spill). Staging from the
// pre-transposed f16 Xh: each owned position = 2x global_load_dwordx4 + 2x
// ds_write_b128 (no cvt, no strided f32). 4-slot ring, ONE barrier per t; the
// t+2 prefetch loads are issued AFTER the barrier so they remain in flight
// across the full compute phase (consumed by commit at the next iter top).
__global__ __launch_bounds__(256, 2)
void qrnn_xh_kernel(const _Float16* __restrict__ Xh, const _Float16* __restrict__ WA,
                    const float* __restrict__ bias, float* __restrict__ out) {
    __shared__ __align__(16) char smem[LDSF];

    const int tid  = threadIdx.x;
    const int lane = tid & 63;
    const int wv   = tid >> 6;            // wave 0..3 -> w segment [wv*32, wv*32+32)

    // XCD-bijective swizzle (512 wgs, 8 XCDs)
    const int swz = (blockIdx.x & 7) * 64 + (blockIdx.x >> 3);
    const int b = swz >> 7;
    const int h = swz & 127;

    const size_t strideT = (size_t)Hn * Wn;        // 16384
    const size_t strideC = (size_t)Tn * strideT;   // 507904

    const int lane15  = lane & 15;
    const int g       = lane >> 4;        // k-group 0..3
    const int ghi     = g >> 1;           // tap within K-step pair
    const int e       = g & 1;            // cin half
    const int laneoff = lane15 * POSB + e * 16;
    const int wbase   = wv * 32;

    // bias per thread: hid = g*4 + r (C-frag row = (lane>>4)*4 + reg)
    float bz[4], bfv[4], bov[4], biv[4];
    #pragma unroll
    for (int r = 0; r < 4; r++) {
        int hid = g * 4 + r;
        bz[r]  = bias[hid];
        bfv[r] = bias[HIDn + hid];
        bov[r] = bias[2 * HIDn + hid];
        biv[r] = bias[3 * HIDn + hid];
    }

    // --- staging descriptors: 390 positions (3 rows x 130 wpos), <=2 per thread ---
    const char* XhB = (const char*)Xh + (size_t)b * Tn * SLICE_B;
    bool own[2], inb[2]; int soff[2], loff[2];
    #pragma unroll
    for (int k = 0; k < 2; k++) {
        int p  = tid + (k << 8);
        own[k] = (p < 3 * 130);
        int r    = (p >= 260) ? 2 : (p >= 130) ? 1 : 0;
        int wpos = p - r * 130;
        int hr = h - 1 + r;
        int wa = wpos - 1;
        inb[k]  = own[k] && (hr >= 0) && (hr < Hn) && (wa >= 0) && (wa < Wn);
        soff[k] = (hr * Wn + wa) * 32;
        loff[k] = r * ROWF + wpos * POSB;
    }

    half8 pfA[2], pfB[2];     // in-flight slice data (already f16, no cvt)

    auto issue = [&](int u) {
        const bool uok = (u >= 0) && (u < Tn);
        #pragma unroll
        for (int k = 0; k < 2; k++) {
            half8 a = {}, c = {};
            if (uok && inb[k]) {
                const char* s = XhB + (size_t)u * SLICE_B + soff[k];
                a = *reinterpret_cast<const half8*>(s);
                c = *reinterpret_cast<const half8*>(s + 16);
            }
            pfA[k] = a; pfB[k] = c;
        }
    };
    auto commit = [&](int u) {
        char* sl = smem + (u & 3) * SLOTF;
        #pragma unroll
        for (int k = 0; k < 2; k++) if (own[k]) {
            *reinterpret_cast<half8*>(sl + loff[k])      = pfA[k];
            *reinterpret_cast<half8*>(sl + loff[k] + 16) = pfB[k];
        }
    };

    // prologue: slot 3 (u=-1) = zeros; commit u=0; issue u=1
    {
        half8 z = {};
        #pragma unroll
        for (int k = 0; k < 2; k++) if (own[k]) {
            *reinterpret_cast<half8*>(smem + 3 * SLOTF + loff[k])      = z;
            *reinterpret_cast<half8*>(smem + 3 * SLOTF + loff[k] + 16) = z;
        }
    }
    issue(0);
    commit(0);
    issue(1);

    float cst[2][4];
    #pragma unroll
    for (int n = 0; n < 2; n++)
        #pragma unroll
        for (int r = 0; r < 4; r++) cst[n][r] = 0.f;

    float* outb = out + (size_t)b * HIDn * strideC + (size_t)h * Wn + wbase + lane15;

    for (int t = 0; t < Tn; t++) {
        commit(t + 1);                 // pf (loaded last iter) -> slot (t+1)&3
        __syncthreads();               // lgkm drain publishes it; ring safety
        issue(t + 2);                  // loads in flight across full compute phase

        const int sb[3] = { ((t + 3) & 3) * SLOTF, (t & 3) * SLOTF, ((t + 1) & 3) * SLOTF };

        f32x4 acc[2][4];
        #pragma unroll
        for (int n = 0; n < 2; n++)
            #pragma unroll
            for (int m = 0; m < 4; m++) acc[n][m] = (f32x4)(0.f);

        #pragma unroll
        for (int s = 0; s < NS; s++) {
            const half8 a0 = *reinterpret_cast<const half8*>(WA + ((size_t)(s * 4 + 0) * 64 + lane) * 8);
            const half8 a1 = *reinterpret_cast<const half8*>(WA + ((size_t)(s * 4 + 1) * 64 + lane) * 8);
            const half8 a2 = *reinterpret_cast<const half8*>(WA + ((size_t)(s * 4 + 2) * 64 + lane) * 8);
            const half8 a3 = *reinterpret_cast<const half8*>(WA + ((size_t)(s * 4 + 3) * 64 + lane) * 8);

            const int tA = 2 * s, tB = 2 * s + 1;        // compile-time taps
            const int offA = sb[KDt[tA]] + KHt[tA] * ROWF + KWt[tA] * POSB;
            const int offB = sb[KDt[tB]] + KHt[tB] * ROWF + KWt[tB] * POSB;
            const int off  = (ghi ? offB : offA) + laneoff;

            #pragma unroll
            for (int n = 0; n < 2; n++) {
                const half8 bf = *reinterpret_cast<const half8*>(
                    smem + off + (wbase + n * 16) * POSB);
                acc[n][0] = __builtin_amdgcn_mfma_f32_16x16x32_f16(a0, bf, acc[n][0], 0, 0, 0);
                acc[n][1] = __builtin_amdgcn_mfma_f32_16x16x32_f16(a1, bf, acc[n][1], 0, 0, 0);
                acc[n][2] = __builtin_amdgcn_mfma_f32_16x16x32_f16(a2, bf, acc[n][2], 0, 0, 0);
                acc[n][3] = __builtin_amdgcn_mfma_f32_16x16x32_f16(a3, bf, acc[n][3], 0, 0, 0);
            }
        }

        // epilogue: oc-tile m = gate m (z,f,o,i) for hid = g*4+r, col = wbase+n*16+lane15
        #pragma unroll
        for (int n = 0; n < 2; n++) {
            #pragma unroll
            for (int r = 0; r < 4; r++) {
                float z = tanhf_   (acc[n][0][r] + bz[r]);
                float f = sigmoidf_(acc[n][1][r] + bfv[r]);
                float o = sigmoidf_(acc[n][2][r] + bov[r]);
                float i = sigmoidf_(acc[n][3][r] + biv[r]);
                float c = f * cst[n][r] + i * z;
                cst[n][r] = c;
                outb[(size_t)(g * 4 + r) * strideC + (size_t)t * strideT + n * 16] = o * c;
            }
        }
        // no trailing barrier: 4-slot ring keeps next iter's writes disjoint from
        // any slot a <=1-iteration-lagging wave can still be reading.
    }
}

// =====================  FALLBACK (round-1 harness-verified; used if ws too small)  =====================
#define WSTR  48
#define ROWB  (130*WSTR)
#define SLOT3 (3*ROWB)
#define LDS3  (3*SLOT3)

__global__ __launch_bounds__(256, 2)
void qrnn_fb_kernel(const float* __restrict__ X, const _Float16* __restrict__ WA,
                    const float* __restrict__ bias, float* __restrict__ out) {
    __shared__ __align__(16) char smem[LDS3];
    const int tid  = threadIdx.x;
    const int lane = tid & 63;
    const int wv   = tid >> 6;
    const int swz = (blockIdx.x & 7) * 64 + (blockIdx.x >> 3);
    const int b = swz >> 7;
    const int h = swz & 127;
    const size_t strideT = (size_t)Hn * Wn;
    const size_t strideC = (size_t)Tn * strideT;
    const float* Xb = X + (size_t)b * CINn * strideC;
    const int lane15  = lane & 15;
    const int g       = lane >> 4;
    const int ghi     = g >> 1;
    const int laneoff = lane15 * WSTR + (g & 1) * 16;
    const int wbase   = wv * 32;
    float bz[4], bfv[4], bov[4], biv[4];
    #pragma unroll
    for (int r = 0; r < 4; r++) {
        int hid = g * 4 + r;
        bz[r] = bias[hid]; bfv[r] = bias[HIDn + hid];
        bov[r] = bias[2 * HIDn + hid]; biv[r] = bias[3 * HIDn + hid];
    }
    auto stage = [&](int u, int s) {
        const bool uok = (u >= 0) && (u < Tn);
        for (int p = tid; p < 3 * 130; p += 256) {
            int row  = (p >= 260) ? 2 : (p >= 130) ? 1 : 0;
            int wpos = p - row * 130;
            int hr = h - 1 + row;
            int wa = wpos - 1;
            bool valid = uok && (hr >= 0) && (hr < Hn) && (wa >= 0) && (wa < Wn);
            const float* src = Xb + (ptrdiff_t)u * (ptrdiff_t)strideT + (ptrdiff_t)hr * Wn + wa;
            half8 h0, h1;
            #pragma unroll
            for (int c8 = 0; c8 < 8; c8++) h0[c8] = valid ? (_Float16)src[(size_t)c8 * strideC] : (_Float16)0.f;
            #pragma unroll
            for (int c8 = 0; c8 < 8; c8++) h1[c8] = valid ? (_Float16)src[(size_t)(8 + c8) * strideC] : (_Float16)0.f;
            char* dst = smem + s * SLOT3 + row * ROWB + wpos * WSTR;
            *reinterpret_cast<half8*>(dst)      = h0;
            *reinterpret_cast<half8*>(dst + 16) = h1;
        }
    };
    float cst[2][4];
    #pragma unroll
    for (int n = 0; n < 2; n++)
        #pragma unroll
        for (int r = 0; r < 4; r++) cst[n][r] = 0.f;
    stage(-1, 2);
    stage(0, 0);
    float* outb = out + (size_t)b * HIDn * strideC + (size_t)h * Wn + wbase + lane15;
    for (int t = 0; t < Tn; t++) {
        stage(t + 1, (t + 1) % 3);
        __syncthreads();
        const int sb[3] = { ((t + 2) % 3) * SLOT3, (t % 3) * SLOT3, ((t + 1) % 3) * SLOT3 };
        f32x4 acc[2][4];
        #pragma unroll
        for (int n = 0; n < 2; n++)
            #pragma unroll
            for (int m = 0; m < 4; m++) acc[n][m] = (f32x4)(0.f);
        #pragma unroll
        for (int s = 0; s < NS; s++) {
            const half8 a0 = *reinterpret_cast<const half8*>(WA + ((size_t)(s * 4 + 0) * 64 + lane) * 8);
            const half8 a1 = *reinterpret_cast<const half8*>(WA + ((size_t)(s * 4 + 1) * 64 + lane) * 8);
            const half8 a2 = *reinterpret_cast<const half8*>(WA + ((size_t)(s * 4 + 2) * 64 + lane) * 8);
            const half8 a3 = *reinterpret_cast<const half8*>(WA + ((size_t)(s * 4 + 3) * 64 + lane) * 8);
            const int tA = 2 * s, tB = 2 * s + 1;
            const int offA = sb[KDt[tA]] + KHt[tA] * ROWB + KWt[tA] * WSTR;
            const int offB = sb[KDt[tB]] + KHt[tB] * ROWB + KWt[tB] * WSTR;
            const int off  = (ghi ? offB : offA) + laneoff;
            #pragma unroll
            for (int n = 0; n < 2; n++) {
                const half8 bf = *reinterpret_cast<const half8*>(smem + off + (wbase + n * 16) * WSTR);
                acc[n][0] = __builtin_amdgcn_mfma_f32_16x16x32_f16(a0, bf, acc[n][0], 0, 0, 0);
                acc[n][1] = __builtin_amdgcn_mfma_f32_16x16x32_f16(a1, bf, acc[n][1], 0, 0, 0);
                acc[n][2] = __builtin_amdgcn_mfma_f32_16x16x32_f16(a2, bf, acc[n][2], 0, 0, 0);
                acc[n][3] = __builtin_amdgcn_mfma_f32_16x16x32_f16(a3, bf, acc[n][3], 0, 0, 0);
            }
        }
        #pragma unroll
        for (int n = 0; n < 2; n++) {
            #pragma unroll
            for (int r = 0; r < 4; r++) {
                float z = tanhf_   (acc[n][0][r] + bz[r]);
                float f = sigmoidf_(acc[n][1][r] + bfv[r]);
                float o = sigmoidf_(acc[n][2][r] + bov[r]);
                float i = sigmoidf_(acc[n][3][r] + biv[r]);
                float c = f * cst[n][r] + i * z;
                cst[n][r] = c;
                outb[(size_t)(g * 4 + r) * strideC + (size_t)t * strideT + n * 16] = o * c;
            }
        }
        __syncthreads();
    }
}

// =====================  host  =====================
extern "C" void kernel_launch(void* const* d_in, const int* in_sizes, int n_in,
                              void* d_out, int out_size, void* d_ws, size_t ws_size,
                              hipStream_t stream) {
    const float* X    = (const float*)d_in[0];
    const float* W    = (const float*)d_in[1];
    const float* bias = (const float*)d_in[2];
    float* out = (float*)d_out;

    _Float16* WA = (_Float16*)d_ws;   // 14*4*64*8 = 28672 f16 = 57344 BYTES (ends < XH_OFF)
    repack_wa_kernel<<<(NS * 4 * 64 * 8 + 255) / 256, 256, 0, stream>>>(W, WA);

    if (ws_size >= WS_NEED) {
        _Float16* Xh = (_Float16*)((char*)d_ws + XH_OFF);
        transpose_x_kernel<<<(Bn * Tn * Hn * Wn) / 256, 256, 0, stream>>>(X, Xh);
        qrnn_xh_kernel<<<Bn * Hn, 256, 0, stream>>>(Xh, WA, bias, out);
    } else {
        qrnn_fb_kernel<<<Bn * Hn, 256, 0, stream>>>(X, WA, bias, out);
    }
}